// Round 10
// baseline (131.588 us; speedup 1.0000x reference)
//
#include <hip/hip_runtime.h>
#include <hip/hip_bf16.h>
#include <math.h>

#define DIM  64
#define KN   16
#define NREL 32
#define S4   0.00390625f   // 1/256: undo the x256 fp4 storage scale

__device__ __forceinline__ float frcp(float x) { return __builtin_amdgcn_rcpf(x); }

__device__ __forceinline__ unsigned short f2bf(float f) {
    unsigned u = __float_as_uint(f);
    u = (u + 0x7fffu + ((u >> 16) & 1u)) >> 16;   // RNE
    return (unsigned short)u;
}

// fp4 e2m1 encode (values pre-scaled x256): codes 0,.5,1,1.5,2,3,4,6 + sign<<3
__device__ __forceinline__ unsigned enc4(float x) {
    const float a = fabsf(x) * 256.f;
    const unsigned s = (x < 0.f) ? 8u : 0u;
    const unsigned c =
        (a < 0.25f) ? 0u :
        (a < 0.75f) ? 1u :
        (a < 1.25f) ? 2u :
        (a < 1.75f) ? 3u :
        (a < 2.5f ) ? 4u :
        (a < 3.5f ) ? 5u :
        (a < 5.0f ) ? 6u : 7u;
    return s | c;
}

typedef __attribute__((ext_vector_type(8))) short bfrag;   // 8 bf16 (4 VGPRs)
typedef __attribute__((ext_vector_type(4))) float f32x4;   // MFMA accumulator

// ============================================================================
// Kernel 1 (R20): WE precompute as MFMA GEMM -> fp4 e2m1 table (32 B/row),
// stored x256. Hot set becomes WE4 3.2MB + adjP 6.4MB = 9.6MB (was 12.8),
// raising per-XCD L2 hit rate on the line-fetch bottleneck (R19's confirmed
// lever). Adjacency packing unchanged.
// ============================================================================
__global__ __launch_bounds__(256, 2) void we_kernel_mfma(
    const float* __restrict__ entity_emb,
    const float* __restrict__ W,
    const int* __restrict__ adjE,
    const int* __restrict__ adjR,
    unsigned char* __restrict__ WE4,
    int* __restrict__ adjP,
    int nRows)
{
    const int tid  = threadIdx.x;
    const int wave = tid >> 6;
    const int lane = tid & 63;
    const int c = lane & 15;
    const int g = lane >> 4;

    // ---- pack adjacency: 8 entries per thread, int4 vectorized ----
    {
        const size_t nEntries = (size_t)nRows * KN;
        const size_t base = ((size_t)blockIdx.x * 256 + tid) * 8;
        if (base + 8 <= nEntries) {
            const int4* e4 = (const int4*)(adjE + base);
            const int4* r4 = (const int4*)(adjR + base);
            const int4 e0 = e4[0], e1v = e4[1];
            const int4 r0 = r4[0], r1v = r4[1];
            int4 p0, p1;
            p0.x = (e0.x << 5) | r0.x;  p0.y = (e0.y << 5) | r0.y;
            p0.z = (e0.z << 5) | r0.z;  p0.w = (e0.w << 5) | r0.w;
            p1.x = (e1v.x << 5) | r1v.x; p1.y = (e1v.y << 5) | r1v.y;
            p1.z = (e1v.z << 5) | r1v.z; p1.w = (e1v.w << 5) | r1v.w;
            ((int4*)(adjP + base))[0] = p0;
            ((int4*)(adjP + base))[1] = p1;
        } else if (base < nEntries) {
            for (size_t i = base; i < nEntries; ++i)
                adjP[i] = (adjE[i] << 5) | adjR[i];
        }
    }

    const int nTiles = (nRows + 15) >> 4;
    const int t0 = (blockIdx.x * 4 + wave) * 2;       // 2 tiles per wave
    if (t0 >= nTiles) return;

    bfrag a[4][2];
    #pragma unroll
    for (int m = 0; m < 4; ++m) {
        #pragma unroll
        for (int ks = 0; ks < 2; ++ks) {
            const float4* ws = (const float4*)(W + (size_t)(16 * m + c) * DIM + 8 * g + 32 * ks);
            const float4 w0 = ws[0], w1 = ws[1];
            a[m][ks][0] = (short)f2bf(w0.x); a[m][ks][1] = (short)f2bf(w0.y);
            a[m][ks][2] = (short)f2bf(w0.z); a[m][ks][3] = (short)f2bf(w0.w);
            a[m][ks][4] = (short)f2bf(w1.x); a[m][ks][5] = (short)f2bf(w1.y);
            a[m][ks][6] = (short)f2bf(w1.z); a[m][ks][7] = (short)f2bf(w1.w);
        }
    }

    float4 pe[2][4];
    #pragma unroll
    for (int j = 0; j < 2; ++j) {
        const int t = (t0 + j < nTiles) ? (t0 + j) : 0;
        int row = 16 * t + c;
        if (row >= nRows) row = nRows - 1;
        const float4* src = (const float4*)(entity_emb + (size_t)row * DIM + 8 * g);
        pe[j][0] = src[0];
        pe[j][1] = src[1];
        pe[j][2] = src[8];
        pe[j][3] = src[9];
    }

    #pragma unroll
    for (int j = 0; j < 2; ++j) {
        const int t = t0 + j;
        if (t >= nTiles) continue;

        bfrag b0, b1;
        b0[0] = (short)f2bf(pe[j][0].x); b0[1] = (short)f2bf(pe[j][0].y);
        b0[2] = (short)f2bf(pe[j][0].z); b0[3] = (short)f2bf(pe[j][0].w);
        b0[4] = (short)f2bf(pe[j][1].x); b0[5] = (short)f2bf(pe[j][1].y);
        b0[6] = (short)f2bf(pe[j][1].z); b0[7] = (short)f2bf(pe[j][1].w);
        b1[0] = (short)f2bf(pe[j][2].x); b1[1] = (short)f2bf(pe[j][2].y);
        b1[2] = (short)f2bf(pe[j][2].z); b1[3] = (short)f2bf(pe[j][2].w);
        b1[4] = (short)f2bf(pe[j][3].x); b1[5] = (short)f2bf(pe[j][3].y);
        b1[6] = (short)f2bf(pe[j][3].z); b1[7] = (short)f2bf(pe[j][3].w);

        f32x4 acc[4];
        #pragma unroll
        for (int m = 0; m < 4; ++m) {
            f32x4 z = {0.f, 0.f, 0.f, 0.f};
            z = __builtin_amdgcn_mfma_f32_16x16x32_bf16(a[m][0], b0, z, 0, 0, 0);
            z = __builtin_amdgcn_mfma_f32_16x16x32_bf16(a[m][1], b1, z, 0, 0, 0);
            acc[m] = z;
        }

        const int erow = 16 * t + c;
        if (erow < nRows) {
            #pragma unroll
            for (int m = 0; m < 4; ++m) {
                // fp4 row: lane owns dims 16m+4g..+3 -> 16 bits at byte 8m+2g
                const unsigned pk = enc4(acc[m][0])
                                  | (enc4(acc[m][1]) << 4)
                                  | (enc4(acc[m][2]) << 8)
                                  | (enc4(acc[m][3]) << 12);
                *(unsigned short*)(WE4 + (size_t)erow * 32 + 8 * m + 2 * g) =
                    (unsigned short)pk;
            }
        }
    }
}

// ============================================================================
// Kernel 2 (R20): all WE reads from the 3.2MB fp4 table (32 B rows, ushort
// per lane). Decode via per-wave 16-entry LDS LUT (no cross-wave barrier).
// Structure = verified R19 form. Hot set 9.6MB targets L2 hit rate.
// ============================================================================
__global__ __launch_bounds__(256, 4) void kgcn_main(
    const int* __restrict__ pairs,
    const int* __restrict__ adjP,
    const unsigned char* __restrict__ WE4,
    const float* __restrict__ relation_emb,
    const float* __restrict__ user_emb,
    const float* __restrict__ W,
    const float* __restrict__ bias,
    float* __restrict__ out,
    int nPairs)
{
    __shared__ float ev1_s[4][KN * DIM];  // per-wave layer-0 outputs
    __shared__ float xb_s[4][DIM];        // per-wave matvec broadcast buffer
    __shared__ float lut_s[4][16];        // per-wave fp4 decode LUT

    const int tid  = threadIdx.x;
    const int wave = tid >> 6;
    const int lane = tid & 63;
    const int p    = blockIdx.x * 4 + wave;
    if (p >= nPairs) return;              // no barriers -> safe early-out

    float* ev1 = ev1_s[wave];
    float* xb  = xb_s[wave];
    const float* lut = lut_s[wave];

    // fill this wave's LUT (wave-local; lgkmcnt orders it before use)
    if (lane < 16) {
        const int m = lane & 7;
        float v = (m < 2) ? 0.5f * (float)m
                          : __uint_as_float(((126u + (unsigned)(m >> 1)) << 23) |
                                            (((unsigned)m & 1u) << 22));
        lut_s[wave][lane] = (lane & 8) ? -v : v;
    }

    const int qq = lane >> 4;             // quarter-wave id (0..3)
    const int c  = lane & 15;             // ushort column within a WE4 row
    const int c4 = c * 4;                 // first owned dim

    const int user = pairs[2 * p + 0];
    const int item = pairs[2 * p + 1];

    const float4 b4 = *(const float4*)(bias + c4);
    const unsigned short* W4q = (const unsigned short*)WE4;  // row = 16 ushorts

    // ---- chase root: item packed adjacency row (single load) ----
    int rk0 = 0, e1 = 0;
    if (lane < KN) {
        const int pk0 = adjP[(size_t)item * KN + lane];
        rk0 = pk0 & 31;
        e1  = pk0 >> 5;
    }

    // ---- independent: user/relation rows into regs (fly during e1 wait) ----
    float4 rr[8], ur[8];
    {
        const int r = lane >> 1, hlf = lane & 1;
        const float4* rel4 = (const float4*)(relation_emb + r * DIM + hlf * 32);
        const float4* u4   = (const float4*)(user_emb + (size_t)user * DIM + hlf * 32);
        #pragma unroll
        for (int j = 0; j < 8; ++j) { rr[j] = rel4[j]; ur[j] = u4[j]; }
    }

    // ---- e1 arrival gates: hop-0 rows + slot adjacency (issue ASAP) ----
    const unsigned itemv4 = W4q[(size_t)item * 16 + c];
    unsigned h0v4[4];
    #pragma unroll
    for (int k = 0; k < 4; ++k) {
        const int e = __shfl(e1, qq * 4 + k);
        h0v4[k] = W4q[(size_t)(unsigned)e * 16 + c];
    }
    int rkA[4], ekA[4], gsA[4];
    #pragma unroll
    for (int s = 0; s < 4; ++s) {
        gsA[s] = __shfl(e1, 4 * s + qq);
        const int pk = adjP[(size_t)(unsigned)gsA[s] * KN + c];
        rkA[s] = pk & 31;
        ekA[s] = pk >> 5;
    }

    // ---- dot(u, rel_r) ----
    float acc;
    {
        float a0 = 0.f, a1 = 0.f;
        #pragma unroll
        for (int j = 0; j < 8; j += 2) {
            float4 a = rr[j],     b = ur[j];
            float4 cc = rr[j+1],  d = ur[j+1];
            a0 += a.x*b.x + a.y*b.y + a.z*b.z + a.w*b.w;
            a1 += cc.x*d.x + cc.y*d.y + cc.z*d.z + cc.w*d.w;
        }
        acc = a0 + a1;
        acc += __shfl_xor(acc, 1);
    }

    // ---- ISSUE hop-1 gathers for slots 0..2 + self rows (2 B/lane) ----
    unsigned svA4[4];
    unsigned nvA[3][KN];
    #pragma unroll
    for (int s = 0; s < 3; ++s) {
        svA4[s] = W4q[(size_t)(unsigned)gsA[s] * 16 + c];
        #pragma unroll
        for (int k = 0; k < KN; ++k) {
            const int e = __shfl(ekA[s], qq * 16 + k);
            nvA[s][k] = W4q[(size_t)(unsigned)e * 16 + c];
        }
    }
    svA4[3] = W4q[(size_t)(unsigned)gsA[3] * 16 + c];

    // softmax within 16-lane subgroups (4 independent groups per call)
    auto softmax16 = [&](float s) -> float {
        float mx = s;
        mx = fmaxf(mx, __shfl_xor(mx, 1));
        mx = fmaxf(mx, __shfl_xor(mx, 2));
        mx = fmaxf(mx, __shfl_xor(mx, 4));
        mx = fmaxf(mx, __shfl_xor(mx, 8));
        float e = __expf(s - mx);
        float ss = e;
        ss += __shfl_xor(ss, 1);
        ss += __shfl_xor(ss, 2);
        ss += __shfl_xor(ss, 4);
        ss += __shfl_xor(ss, 8);
        return e * frcp(ss);
    };

    // fp4 decode: nibble i of packed ushort v
    auto d4 = [&](unsigned v, int i) -> float {
        return lut[(v >> (4 * i)) & 15u];
    };

    // ---- softmaxes run UNDER the gather flight ----
    float wA[4];
    #pragma unroll
    for (int s = 0; s < 4; ++s) wA[s] = softmax16(__shfl(acc, rkA[s] << 1)) * S4;
    const float w0 = softmax16(__shfl(acc, rk0 << 1));   // unscaled: weights f32 ev1 too

    asm volatile("s_waitcnt lgkmcnt(0)" ::: "memory");   // LUT visible (wave-local)

    // ---- consume slot 0, then issue slot 3's neighbors ----
    {
        float ax = b4.x + S4 * d4(svA4[0], 0);
        float ay = b4.y + S4 * d4(svA4[0], 1);
        float az = b4.z + S4 * d4(svA4[0], 2);
        float aw = b4.w + S4 * d4(svA4[0], 3);
        #pragma unroll
        for (int k = 0; k < KN; ++k) {
            const float w = __shfl(wA[0], qq * 16 + k);
            const unsigned v = nvA[0][k];
            ax += w * d4(v, 0);
            ay += w * d4(v, 1);
            az += w * d4(v, 2);
            aw += w * d4(v, 3);
        }
        *(float4*)&ev1[qq * DIM + c4] =
            make_float4(fmaxf(ax, 0.f), fmaxf(ay, 0.f), fmaxf(az, 0.f), fmaxf(aw, 0.f));
    }
    unsigned nv3[KN];
    #pragma unroll
    for (int k = 0; k < KN; ++k) {
        const int e = __shfl(ekA[3], qq * 16 + k);
        nv3[k] = W4q[(size_t)(unsigned)e * 16 + c];
    }
    #pragma unroll
    for (int s = 1; s < 3; ++s) {
        float ax = b4.x + S4 * d4(svA4[s], 0);
        float ay = b4.y + S4 * d4(svA4[s], 1);
        float az = b4.z + S4 * d4(svA4[s], 2);
        float aw = b4.w + S4 * d4(svA4[s], 3);
        #pragma unroll
        for (int k = 0; k < KN; ++k) {
            const float w = __shfl(wA[s], qq * 16 + k);
            const unsigned v = nvA[s][k];
            ax += w * d4(v, 0);
            ay += w * d4(v, 1);
            az += w * d4(v, 2);
            aw += w * d4(v, 3);
        }
        *(float4*)&ev1[(4 * s + qq) * DIM + c4] =
            make_float4(fmaxf(ax, 0.f), fmaxf(ay, 0.f), fmaxf(az, 0.f), fmaxf(aw, 0.f));
    }
    {
        float ax = b4.x + S4 * d4(svA4[3], 0);
        float ay = b4.y + S4 * d4(svA4[3], 1);
        float az = b4.z + S4 * d4(svA4[3], 2);
        float aw = b4.w + S4 * d4(svA4[3], 3);
        #pragma unroll
        for (int k = 0; k < KN; ++k) {
            const float w = __shfl(wA[3], qq * 16 + k);
            const unsigned v = nv3[k];
            ax += w * d4(v, 0);
            ay += w * d4(v, 1);
            az += w * d4(v, 2);
            aw += w * d4(v, 3);
        }
        *(float4*)&ev1[(12 + qq) * DIM + c4] =
            make_float4(fmaxf(ax, 0.f), fmaxf(ay, 0.f), fmaxf(az, 0.f), fmaxf(aw, 0.f));
    }

    // ---- hop 0, layer 0: accumulate the preloaded fp4 rows ----
    float ax = 0.f, ay = 0.f, az = 0.f, aw = 0.f;
    #pragma unroll
    for (int k = 0; k < 4; ++k) {
        const float w = __shfl(w0, qq * 4 + k) * S4;
        const unsigned v = h0v4[k];
        ax += w * d4(v, 0);
        ay += w * d4(v, 1);
        az += w * d4(v, 2);
        aw += w * d4(v, 3);
    }
    ax += __shfl_xor(ax, 16); ay += __shfl_xor(ay, 16);
    az += __shfl_xor(az, 16); aw += __shfl_xor(aw, 16);
    ax += __shfl_xor(ax, 32); ay += __shfl_xor(ay, 32);
    az += __shfl_xor(az, 32); aw += __shfl_xor(aw, 32);
    ax += S4 * d4(itemv4, 0) + b4.x;
    ay += S4 * d4(itemv4, 1) + b4.y;
    az += S4 * d4(itemv4, 2) + b4.z;
    aw += S4 * d4(itemv4, 3) + b4.w;
    const float e0x = fmaxf(ax, 0.f), e0y = fmaxf(ay, 0.f);
    const float e0z = fmaxf(az, 0.f), e0w = fmaxf(aw, 0.f);

    // ---- layer 1 aggregate: x1 = e0 + sum_k w0_k * ev1_k (f32, unscaled w0)
    asm volatile("s_waitcnt lgkmcnt(0)" ::: "memory");  // ev1 writes done (wave-local)
    float sx = 0.f, sy = 0.f, sz = 0.f, sw = 0.f;
    #pragma unroll
    for (int k = 0; k < 4; ++k) {
        const int   kg = qq * 4 + k;
        const float w  = __shfl(w0, kg);
        float4 ev = *(const float4*)&ev1[kg * DIM + c4];
        sx += w * ev.x;
        sy += w * ev.y;
        sz += w * ev.z;
        sw += w * ev.w;
    }
    sx += __shfl_xor(sx, 16); sy += __shfl_xor(sy, 16);
    sz += __shfl_xor(sz, 16); sw += __shfl_xor(sw, 16);
    sx += __shfl_xor(sx, 32); sy += __shfl_xor(sy, 32);
    sz += __shfl_xor(sz, 32); sw += __shfl_xor(sw, 32);

    // ---- the ONE real matvec: h1 = W x1 + b, via LDS broadcast ----
    asm volatile("s_waitcnt lgkmcnt(0)" ::: "memory");
    if (qq == 0)
        *(float4*)&xb[c4] = make_float4(e0x + sx, e0y + sy, e0z + sz, e0w + sw);
    asm volatile("s_waitcnt lgkmcnt(0)" ::: "memory");
    float h0 = bias[lane], h1 = 0.f, h2 = 0.f, h3 = 0.f;
    {
        const float4* Wl  = (const float4*)(W + lane * DIM);
        const float4* xv4 = (const float4*)xb;
        #pragma unroll
        for (int j = 0; j < 16; j += 4) {
            float4 w0v = Wl[j],   x0v = xv4[j];
            float4 w1v = Wl[j+1], x1v = xv4[j+1];
            float4 w2v = Wl[j+2], x2v = xv4[j+2];
            float4 w3v = Wl[j+3], x3v = xv4[j+3];
            h0 += w0v.x*x0v.x + w0v.y*x0v.y + w0v.z*x0v.z + w0v.w*x0v.w;
            h1 += w1v.x*x1v.x + w1v.y*x1v.y + w1v.z*x1v.z + w1v.w*x1v.w;
            h2 += w2v.x*x2v.x + w2v.y*x2v.y + w2v.z*x2v.z + w2v.w*x2v.w;
            h3 += w3v.x*x3v.x + w3v.y*x3v.y + w3v.z*x3v.z + w3v.w*x3v.w;
        }
    }
    const float itemf = tanhf((h0 + h1) + (h2 + h3));

    float d = user_emb[(size_t)user * DIM + lane] * itemf;
    d += __shfl_xor(d, 1);
    d += __shfl_xor(d, 2);
    d += __shfl_xor(d, 4);
    d += __shfl_xor(d, 8);
    d += __shfl_xor(d, 16);
    d += __shfl_xor(d, 32);
    if (lane == 0) out[p] = 1.f / (1.f + expf(-d));
}

// ============================================================================
// Fallback (verified R5 kernel) in case ws_size < table sizes.
// ============================================================================
__global__ __launch_bounds__(256, 4) void kgcn_fallback(
    const int* __restrict__ pairs, const int* __restrict__ adj_entity,
    const int* __restrict__ adj_relation, const float* __restrict__ entity_emb,
    const float* __restrict__ relation_emb, const float* __restrict__ user_emb,
    const float* __restrict__ W, const float* __restrict__ bias,
    float* __restrict__ out, int nPairs)
{
    __shared__ float ev1_s[2][KN * DIM];
    __shared__ float xb_s[4][DIM];
    const int tid = threadIdx.x, wave = tid >> 6, lane = tid & 63;
    const int q = wave >> 1, half = wave & 1;
    int p = blockIdx.x * 2 + q;
    if (p >= nPairs) p = nPairs - 1;
    float* ev1 = ev1_s[q]; float* xb = xb_s[wave];
    const int user = pairs[2 * p + 0], item = pairs[2 * p + 1];
    const float bval = bias[lane];
    const float* emb_l = entity_emb + lane;
    const float4* W4 = (const float4*)(W + lane * DIM);
    int rk0 = 0, e1 = 0;
    if (lane < KN) {
        rk0 = adj_relation[(size_t)item * KN + lane];
        e1  = adj_entity[(size_t)item * KN + lane];
    }
    float acc;
    {
        const int r = lane >> 1, hlf = lane & 1;
        const float4* rel4 = (const float4*)(relation_emb + r * DIM + hlf * 32);
        const float4* u4 = (const float4*)(user_emb + (size_t)user * DIM + hlf * 32);
        float a0 = 0.f, a1 = 0.f;
        #pragma unroll
        for (int j = 0; j < 8; j += 2) {
            float4 a = rel4[j], b = u4[j], c = rel4[j+1], d = u4[j+1];
            a0 += a.x*b.x + a.y*b.y + a.z*b.z + a.w*b.w;
            a1 += c.x*d.x + c.y*d.y + c.z*d.z + c.w*d.w;
        }
        acc = a0 + a1; acc += __shfl_xor(acc, 1);
    }
    auto softmax16 = [&](float s) -> float {
        float mx = s;
        mx = fmaxf(mx, __shfl_xor(mx, 1)); mx = fmaxf(mx, __shfl_xor(mx, 2));
        mx = fmaxf(mx, __shfl_xor(mx, 4)); mx = fmaxf(mx, __shfl_xor(mx, 8));
        float e = __expf(s - mx);
        float ss = e;
        ss += __shfl_xor(ss, 1); ss += __shfl_xor(ss, 2);
        ss += __shfl_xor(ss, 4); ss += __shfl_xor(ss, 8);
        return e * frcp(ss);
    };
    auto matvec = [&](float xv) -> float {
        asm volatile("s_waitcnt lgkmcnt(0)" ::: "memory");
        xb[lane] = xv;
        asm volatile("s_waitcnt lgkmcnt(0)" ::: "memory");
        float h0 = bval, h1 = 0.f, h2 = 0.f, h3 = 0.f;
        const float4* xv4 = (const float4*)xb;
        #pragma unroll
        for (int j = 0; j < 16; j += 4) {
            float4 w0 = W4[j], x0 = xv4[j], w1 = W4[j+1], x1 = xv4[j+1];
            float4 w2 = W4[j+2], x2 = xv4[j+2], w3 = W4[j+3], x3 = xv4[j+3];
            h0 += w0.x*x0.x + w0.y*x0.y + w0.z*x0.z + w0.w*x0.w;
            h1 += w1.x*x1.x + w1.y*x1.y + w1.z*x1.z + w1.w*x1.w;
            h2 += w2.x*x2.x + w2.y*x2.y + w2.z*x2.z + w2.w*x2.w;
            h3 += w3.x*x3.x + w3.y*x3.y + w3.z*x3.z + w3.w*x3.w;
        }
        return (h0 + h1) + (h2 + h3);
    };
    auto gather = [&](int self, int ek, float w) -> float {
        float xa = emb_l[(size_t)(unsigned)self * DIM], xc = 0.f;
        #pragma unroll
        for (int k = 0; k < KN; k += 2) {
            const int e0i = __shfl(ek, k); const float f0 = __shfl(w, k);
            const int e1i = __shfl(ek, k + 1); const float f1 = __shfl(w, k + 1);
            xa += f0 * emb_l[(size_t)(unsigned)e0i * DIM];
            xc += f1 * emb_l[(size_t)(unsigned)e1i * DIM];
        }
        return xa + xc;
    };
    int rk_n = 0, ek_n = 0;
    {
        const int g0 = __shfl(e1, half * 8);
        if (lane < KN) {
            rk_n = adj_relation[(size_t)(unsigned)g0 * KN + lane];
            ek_n = adj_entity[(size_t)(unsigned)g0 * KN + lane];
        }
    }
    #pragma unroll 1
    for (int mi = 0; mi < 8; ++mi) {
        const int m = half * 8 + mi;
        const int g = __shfl(e1, m);
        const int rk = rk_n, ek = ek_n;
        if (mi + 1 < 8) {
            const int gn = __shfl(e1, m + 1);
            if (lane < KN) {
                rk_n = adj_relation[(size_t)(unsigned)gn * KN + lane];
                ek_n = adj_entity[(size_t)(unsigned)gn * KN + lane];
            }
        }
        const float w = softmax16(__shfl(acc, rk << 1));
        const float x = gather(g, ek, w);
        ev1[m * DIM + lane] = fmaxf(matvec(x), 0.f);
    }
    __syncthreads();
    if (half != 0) return;
    const float w0 = softmax16(__shfl(acc, rk0 << 1));
    const float x0 = gather(item, e1, w0);
    const float e0 = fmaxf(matvec(x0), 0.f);
    float xa = e0, xc = 0.f;
    #pragma unroll
    for (int k = 0; k < KN; k += 2) {
        xa += __shfl(w0, k) * ev1[k * DIM + lane];
        xc += __shfl(w0, k + 1) * ev1[(k + 1) * DIM + lane];
    }
    const float itemf = tanhf(matvec(xa + xc));
    float d = user_emb[(size_t)user * DIM + lane] * itemf;
    d += __shfl_xor(d, 1); d += __shfl_xor(d, 2); d += __shfl_xor(d, 4);
    d += __shfl_xor(d, 8); d += __shfl_xor(d, 16); d += __shfl_xor(d, 32);
    if (lane == 0) out[p] = 1.f / (1.f + expf(-d));
}

extern "C" void kernel_launch(void* const* d_in, const int* in_sizes, int n_in,
                              void* d_out, int out_size, void* d_ws, size_t ws_size,
                              hipStream_t stream) {
    const int*   pairs        = (const int*)d_in[0];
    const int*   adj_entity   = (const int*)d_in[1];
    const int*   adj_relation = (const int*)d_in[2];
    const float* entity_emb   = (const float*)d_in[3];
    const float* relation_emb = (const float*)d_in[4];
    const float* user_emb     = (const float*)d_in[5];
    const float* W            = (const float*)d_in[6];
    const float* b            = (const float*)d_in[7];
    float* out = (float*)d_out;

    const int nPairs = in_sizes[0] / 2;          // pairs is (B, 2)
    const int nEnt   = in_sizes[3] / DIM;        // entity count
    const size_t w4Bytes   = (size_t)nEnt * 32;  // fp4 row = 32 B
    const size_t w4Aligned = (w4Bytes + 255) & ~(size_t)255;
    const size_t adjBytes  = (size_t)nEnt * KN * sizeof(int);

    if (ws_size >= w4Aligned + adjBytes) {
        unsigned char* WE4 = (unsigned char*)d_ws;
        int* adjP = (int*)((char*)d_ws + w4Aligned);
        const int nTiles = (nEnt + 15) >> 4;
        const int preBlocks = (nTiles + 7) / 8;   // 2 tiles/wave, 4 waves/block
        we_kernel_mfma<<<preBlocks, 256, 0, stream>>>(entity_emb, W,
                                                      adj_entity, adj_relation,
                                                      WE4, adjP, nEnt);
        const int mainBlocks = (nPairs + 3) / 4;  // 1 wave/pair
        kgcn_main<<<mainBlocks, 256, 0, stream>>>(pairs, adjP,
                                                  WE4, relation_emb, user_emb,
                                                  W, b, out, nPairs);
    } else {
        const int nBlocks = (nPairs + 1) / 2;
        kgcn_fallback<<<nBlocks, 256, 0, stream>>>(pairs, adj_entity, adj_relation,
                                                   entity_emb, relation_emb, user_emb,
                                                   W, b, out, nPairs);
    }
}

// Round 11
// 127.935 us; speedup vs baseline: 1.0286x; 1.0286x over previous
//
#include <hip/hip_runtime.h>
#include <hip/hip_bf16.h>
#include <math.h>

#define DIM  64
#define KN   16
#define NREL 32
#define S8   0.00390625f   // 2^-8: undo the x256 storage scale of the fp8 rows

__device__ __forceinline__ float frcp(float x) { return __builtin_amdgcn_rcpf(x); }

__device__ __forceinline__ unsigned short f2bf(float f) {
    unsigned u = __float_as_uint(f);
    u = (u + 0x7fffu + ((u >> 16) & 1u)) >> 16;   // RNE
    return (unsigned short)u;
}

typedef __attribute__((ext_vector_type(8))) short bfrag;   // 8 bf16 (4 VGPRs)
typedef __attribute__((ext_vector_type(4))) float f32x4;   // MFMA accumulator
typedef __attribute__((ext_vector_type(2))) float f32x2;   // fp8 cvt result

// ============================================================================
// Kernel 1 (R21): WE precompute as MFMA GEMM -> MERGED 128B per-entity record:
//   rec[e] = [ fp8 WE row x256 (64B) | packed adjacency (e<<5|r)x16 (64B) ]
// One cache line now serves both the adjacency AND the self-row of a group
// (previously 2 random lines). Hot set 12.8MB, decode = free hw cvt (R19's
// verified sweet spot); this isolates the line-count lever vs R19.
// ============================================================================
__global__ __launch_bounds__(256, 2) void we_kernel_mfma(
    const float* __restrict__ entity_emb,
    const float* __restrict__ W,
    const int* __restrict__ adjE,
    const int* __restrict__ adjR,
    unsigned char* __restrict__ rec,
    int nRows)
{
    const int tid  = threadIdx.x;
    const int wave = tid >> 6;
    const int lane = tid & 63;
    const int c = lane & 15;
    const int g = lane >> 4;

    // ---- pack adjacency into rec[r]+64: one row per thread ----
    {
        const int r = blockIdx.x * 256 + tid;
        if (r < nRows) {
            const int4* e4 = (const int4*)(adjE + (size_t)r * KN);
            const int4* r4 = (const int4*)(adjR + (size_t)r * KN);
            int4* dst = (int4*)(rec + (size_t)r * 128 + 64);
            #pragma unroll
            for (int j = 0; j < 4; ++j) {
                const int4 e = e4[j], rr = r4[j];
                int4 pk;
                pk.x = (e.x << 5) | rr.x;  pk.y = (e.y << 5) | rr.y;
                pk.z = (e.z << 5) | rr.z;  pk.w = (e.w << 5) | rr.w;
                dst[j] = pk;
            }
        }
    }

    const int nTiles = (nRows + 15) >> 4;
    const int t0 = (blockIdx.x * 4 + wave) * 2;       // 2 tiles per wave
    if (t0 >= nTiles) return;

    bfrag a[4][2];
    #pragma unroll
    for (int m = 0; m < 4; ++m) {
        #pragma unroll
        for (int ks = 0; ks < 2; ++ks) {
            const float4* ws = (const float4*)(W + (size_t)(16 * m + c) * DIM + 8 * g + 32 * ks);
            const float4 w0 = ws[0], w1 = ws[1];
            a[m][ks][0] = (short)f2bf(w0.x); a[m][ks][1] = (short)f2bf(w0.y);
            a[m][ks][2] = (short)f2bf(w0.z); a[m][ks][3] = (short)f2bf(w0.w);
            a[m][ks][4] = (short)f2bf(w1.x); a[m][ks][5] = (short)f2bf(w1.y);
            a[m][ks][6] = (short)f2bf(w1.z); a[m][ks][7] = (short)f2bf(w1.w);
        }
    }

    float4 pe[2][4];
    #pragma unroll
    for (int j = 0; j < 2; ++j) {
        const int t = (t0 + j < nTiles) ? (t0 + j) : 0;
        int row = 16 * t + c;
        if (row >= nRows) row = nRows - 1;
        const float4* src = (const float4*)(entity_emb + (size_t)row * DIM + 8 * g);
        pe[j][0] = src[0];
        pe[j][1] = src[1];
        pe[j][2] = src[8];
        pe[j][3] = src[9];
    }

    #pragma unroll
    for (int j = 0; j < 2; ++j) {
        const int t = t0 + j;
        if (t >= nTiles) continue;

        bfrag b0, b1;
        b0[0] = (short)f2bf(pe[j][0].x); b0[1] = (short)f2bf(pe[j][0].y);
        b0[2] = (short)f2bf(pe[j][0].z); b0[3] = (short)f2bf(pe[j][0].w);
        b0[4] = (short)f2bf(pe[j][1].x); b0[5] = (short)f2bf(pe[j][1].y);
        b0[6] = (short)f2bf(pe[j][1].z); b0[7] = (short)f2bf(pe[j][1].w);
        b1[0] = (short)f2bf(pe[j][2].x); b1[1] = (short)f2bf(pe[j][2].y);
        b1[2] = (short)f2bf(pe[j][2].z); b1[3] = (short)f2bf(pe[j][2].w);
        b1[4] = (short)f2bf(pe[j][3].x); b1[5] = (short)f2bf(pe[j][3].y);
        b1[6] = (short)f2bf(pe[j][3].z); b1[7] = (short)f2bf(pe[j][3].w);

        f32x4 acc[4];
        #pragma unroll
        for (int m = 0; m < 4; ++m) {
            f32x4 z = {0.f, 0.f, 0.f, 0.f};
            z = __builtin_amdgcn_mfma_f32_16x16x32_bf16(a[m][0], b0, z, 0, 0, 0);
            z = __builtin_amdgcn_mfma_f32_16x16x32_bf16(a[m][1], b1, z, 0, 0, 0);
            acc[m] = z;
        }

        const int erow = 16 * t + c;
        if (erow < nRows) {
            #pragma unroll
            for (int m = 0; m < 4; ++m) {
                // fp8 e4m3, values x256 (normal range), 4 dims -> 1 dword
                int r8 = 0;
                r8 = __builtin_amdgcn_cvt_pk_fp8_f32(acc[m][0] * 256.f, acc[m][1] * 256.f, r8, false);
                r8 = __builtin_amdgcn_cvt_pk_fp8_f32(acc[m][2] * 256.f, acc[m][3] * 256.f, r8, true);
                *(unsigned*)(rec + (size_t)erow * 128 + 16 * m + 4 * g) = (unsigned)r8;
            }
        }
    }
}

// ============================================================================
// Kernel 2 (R21): R19 verified structure; all reads through the merged
// record table (row stride 32 dwords: [0..15]=fp8 WE, [16..31]=packed adj).
// Group-self adjacency+row now share one line.
// ============================================================================
__global__ __launch_bounds__(256, 4) void kgcn_main(
    const int* __restrict__ pairs,
    const unsigned* __restrict__ R,       // merged records, 32 dwords/entity
    const float* __restrict__ relation_emb,
    const float* __restrict__ user_emb,
    const float* __restrict__ W,
    const float* __restrict__ bias,
    float* __restrict__ out,
    int nPairs)
{
    __shared__ float ev1_s[4][KN * DIM];  // per-wave layer-0 outputs
    __shared__ float xb_s[4][DIM];        // per-wave matvec broadcast buffer

    const int tid  = threadIdx.x;
    const int wave = tid >> 6;
    const int lane = tid & 63;
    const int p    = blockIdx.x * 4 + wave;
    if (p >= nPairs) return;              // no barriers -> safe early-out

    float* ev1 = ev1_s[wave];
    float* xb  = xb_s[wave];

    const int qq = lane >> 4;             // quarter-wave id (0..3)
    const int c  = lane & 15;             // dword column within a WE row
    const int c4 = c * 4;                 // first owned dim

    const int user = pairs[2 * p + 0];
    const int item = pairs[2 * p + 1];

    const float4 b4 = *(const float4*)(bias + c4);

    // ---- chase root: item record's adjacency half (same line as itemv8) ----
    int rk0 = 0, e1 = 0;
    if (lane < KN) {
        const int pk0 = (int)R[(size_t)item * 32 + 16 + lane];
        rk0 = pk0 & 31;
        e1  = pk0 >> 5;
    }

    // ---- independent: user/relation rows into regs (fly during e1 wait) ----
    float4 rr[8], ur[8];
    {
        const int r = lane >> 1, hlf = lane & 1;
        const float4* rel4 = (const float4*)(relation_emb + r * DIM + hlf * 32);
        const float4* u4   = (const float4*)(user_emb + (size_t)user * DIM + hlf * 32);
        #pragma unroll
        for (int j = 0; j < 8; ++j) { rr[j] = rel4[j]; ur[j] = u4[j]; }
    }

    // ---- e1 arrival gates: hop-0 rows + slot adjacency+self (one line) ----
    const unsigned itemv8 = R[(size_t)item * 32 + c];
    unsigned h0v8[4];
    #pragma unroll
    for (int k = 0; k < 4; ++k) {
        const int e = __shfl(e1, qq * 4 + k);
        h0v8[k] = R[(size_t)(unsigned)e * 32 + c];
    }
    int rkA[4], ekA[4], gsA[4];
    unsigned svA8[4];
    #pragma unroll
    for (int s = 0; s < 4; ++s) {
        gsA[s] = __shfl(e1, 4 * s + qq);
        const size_t base = (size_t)(unsigned)gsA[s] * 32;
        const int pk = (int)R[base + 16 + c];   // adjacency half
        rkA[s] = pk & 31;
        ekA[s] = pk >> 5;
        svA8[s] = R[base + c];                  // self row, SAME cache line
    }

    // ---- dot(u, rel_r) ----
    float acc;
    {
        float a0 = 0.f, a1 = 0.f;
        #pragma unroll
        for (int j = 0; j < 8; j += 2) {
            float4 a = rr[j],     b = ur[j];
            float4 cc = rr[j+1],  d = ur[j+1];
            a0 += a.x*b.x + a.y*b.y + a.z*b.z + a.w*b.w;
            a1 += cc.x*d.x + cc.y*d.y + cc.z*d.z + cc.w*d.w;
        }
        acc = a0 + a1;
        acc += __shfl_xor(acc, 1);
    }

    // ---- ISSUE hop-1 gathers for slots 0..2 (4 B/lane fp8 dword) ----
    unsigned nvA[3][KN];
    #pragma unroll
    for (int s = 0; s < 3; ++s) {
        #pragma unroll
        for (int k = 0; k < KN; ++k) {
            const int e = __shfl(ekA[s], qq * 16 + k);
            nvA[s][k] = R[(size_t)(unsigned)e * 32 + c];
        }
    }

    // softmax within 16-lane subgroups (4 independent groups per call)
    auto softmax16 = [&](float s) -> float {
        float mx = s;
        mx = fmaxf(mx, __shfl_xor(mx, 1));
        mx = fmaxf(mx, __shfl_xor(mx, 2));
        mx = fmaxf(mx, __shfl_xor(mx, 4));
        mx = fmaxf(mx, __shfl_xor(mx, 8));
        float e = __expf(s - mx);
        float ss = e;
        ss += __shfl_xor(ss, 1);
        ss += __shfl_xor(ss, 2);
        ss += __shfl_xor(ss, 4);
        ss += __shfl_xor(ss, 8);
        return e * frcp(ss);
    };

    // ---- softmaxes run UNDER the gather flight ----
    float wA[4];
    #pragma unroll
    for (int s = 0; s < 4; ++s) wA[s] = softmax16(__shfl(acc, rkA[s] << 1)) * S8;
    const float w0 = softmax16(__shfl(acc, rk0 << 1));   // unscaled: weights f32 ev1 too

    // ---- consume slot 0, then issue slot 3's neighbors ----
    {
        const f32x2 slo = __builtin_amdgcn_cvt_pk_f32_fp8(svA8[0], false);
        const f32x2 shi = __builtin_amdgcn_cvt_pk_f32_fp8(svA8[0], true);
        float ax = b4.x + S8 * slo.x;
        float ay = b4.y + S8 * slo.y;
        float az = b4.z + S8 * shi.x;
        float aw = b4.w + S8 * shi.y;
        #pragma unroll
        for (int k = 0; k < KN; ++k) {
            const float w = __shfl(wA[0], qq * 16 + k);
            const f32x2 lo = __builtin_amdgcn_cvt_pk_f32_fp8(nvA[0][k], false);
            const f32x2 hi = __builtin_amdgcn_cvt_pk_f32_fp8(nvA[0][k], true);
            ax += w * lo.x;
            ay += w * lo.y;
            az += w * hi.x;
            aw += w * hi.y;
        }
        *(float4*)&ev1[qq * DIM + c4] =
            make_float4(fmaxf(ax, 0.f), fmaxf(ay, 0.f), fmaxf(az, 0.f), fmaxf(aw, 0.f));
    }
    unsigned nv3[KN];
    #pragma unroll
    for (int k = 0; k < KN; ++k) {
        const int e = __shfl(ekA[3], qq * 16 + k);
        nv3[k] = R[(size_t)(unsigned)e * 32 + c];
    }
    #pragma unroll
    for (int s = 1; s < 3; ++s) {
        const f32x2 slo = __builtin_amdgcn_cvt_pk_f32_fp8(svA8[s], false);
        const f32x2 shi = __builtin_amdgcn_cvt_pk_f32_fp8(svA8[s], true);
        float ax = b4.x + S8 * slo.x;
        float ay = b4.y + S8 * slo.y;
        float az = b4.z + S8 * shi.x;
        float aw = b4.w + S8 * shi.y;
        #pragma unroll
        for (int k = 0; k < KN; ++k) {
            const float w = __shfl(wA[s], qq * 16 + k);
            const f32x2 lo = __builtin_amdgcn_cvt_pk_f32_fp8(nvA[s][k], false);
            const f32x2 hi = __builtin_amdgcn_cvt_pk_f32_fp8(nvA[s][k], true);
            ax += w * lo.x;
            ay += w * lo.y;
            az += w * hi.x;
            aw += w * hi.y;
        }
        *(float4*)&ev1[(4 * s + qq) * DIM + c4] =
            make_float4(fmaxf(ax, 0.f), fmaxf(ay, 0.f), fmaxf(az, 0.f), fmaxf(aw, 0.f));
    }
    {
        const f32x2 slo = __builtin_amdgcn_cvt_pk_f32_fp8(svA8[3], false);
        const f32x2 shi = __builtin_amdgcn_cvt_pk_f32_fp8(svA8[3], true);
        float ax = b4.x + S8 * slo.x;
        float ay = b4.y + S8 * slo.y;
        float az = b4.z + S8 * shi.x;
        float aw = b4.w + S8 * shi.y;
        #pragma unroll
        for (int k = 0; k < KN; ++k) {
            const float w = __shfl(wA[3], qq * 16 + k);
            const f32x2 lo = __builtin_amdgcn_cvt_pk_f32_fp8(nv3[k], false);
            const f32x2 hi = __builtin_amdgcn_cvt_pk_f32_fp8(nv3[k], true);
            ax += w * lo.x;
            ay += w * lo.y;
            az += w * hi.x;
            aw += w * hi.y;
        }
        *(float4*)&ev1[(12 + qq) * DIM + c4] =
            make_float4(fmaxf(ax, 0.f), fmaxf(ay, 0.f), fmaxf(az, 0.f), fmaxf(aw, 0.f));
    }

    // ---- hop 0, layer 0: accumulate the preloaded fp8 rows ----
    float ax = 0.f, ay = 0.f, az = 0.f, aw = 0.f;
    #pragma unroll
    for (int k = 0; k < 4; ++k) {
        const float w = __shfl(w0, qq * 4 + k) * S8;
        const f32x2 lo = __builtin_amdgcn_cvt_pk_f32_fp8(h0v8[k], false);
        const f32x2 hi = __builtin_amdgcn_cvt_pk_f32_fp8(h0v8[k], true);
        ax += w * lo.x;
        ay += w * lo.y;
        az += w * hi.x;
        aw += w * hi.y;
    }
    ax += __shfl_xor(ax, 16); ay += __shfl_xor(ay, 16);
    az += __shfl_xor(az, 16); aw += __shfl_xor(aw, 16);
    ax += __shfl_xor(ax, 32); ay += __shfl_xor(ay, 32);
    az += __shfl_xor(az, 32); aw += __shfl_xor(aw, 32);
    {
        const f32x2 ilo = __builtin_amdgcn_cvt_pk_f32_fp8(itemv8, false);
        const f32x2 ihi = __builtin_amdgcn_cvt_pk_f32_fp8(itemv8, true);
        ax += S8 * ilo.x + b4.x;
        ay += S8 * ilo.y + b4.y;
        az += S8 * ihi.x + b4.z;
        aw += S8 * ihi.y + b4.w;
    }
    const float e0x = fmaxf(ax, 0.f), e0y = fmaxf(ay, 0.f);
    const float e0z = fmaxf(az, 0.f), e0w = fmaxf(aw, 0.f);

    // ---- layer 1 aggregate: x1 = e0 + sum_k w0_k * ev1_k (f32, unscaled w0)
    asm volatile("s_waitcnt lgkmcnt(0)" ::: "memory");  // ev1 writes done (wave-local)
    float sx = 0.f, sy = 0.f, sz = 0.f, sw = 0.f;
    #pragma unroll
    for (int k = 0; k < 4; ++k) {
        const int   kg = qq * 4 + k;
        const float w  = __shfl(w0, kg);
        float4 ev = *(const float4*)&ev1[kg * DIM + c4];
        sx += w * ev.x;
        sy += w * ev.y;
        sz += w * ev.z;
        sw += w * ev.w;
    }
    sx += __shfl_xor(sx, 16); sy += __shfl_xor(sy, 16);
    sz += __shfl_xor(sz, 16); sw += __shfl_xor(sw, 16);
    sx += __shfl_xor(sx, 32); sy += __shfl_xor(sy, 32);
    sz += __shfl_xor(sz, 32); sw += __shfl_xor(sw, 32);

    // ---- the ONE real matvec: h1 = W x1 + b, via LDS broadcast ----
    asm volatile("s_waitcnt lgkmcnt(0)" ::: "memory");
    if (qq == 0)
        *(float4*)&xb[c4] = make_float4(e0x + sx, e0y + sy, e0z + sz, e0w + sw);
    asm volatile("s_waitcnt lgkmcnt(0)" ::: "memory");
    float h0 = bias[lane], h1 = 0.f, h2 = 0.f, h3 = 0.f;
    {
        const float4* Wl  = (const float4*)(W + lane * DIM);
        const float4* xv4 = (const float4*)xb;
        #pragma unroll
        for (int j = 0; j < 16; j += 4) {
            float4 w0v = Wl[j],   x0v = xv4[j];
            float4 w1v = Wl[j+1], x1v = xv4[j+1];
            float4 w2v = Wl[j+2], x2v = xv4[j+2];
            float4 w3v = Wl[j+3], x3v = xv4[j+3];
            h0 += w0v.x*x0v.x + w0v.y*x0v.y + w0v.z*x0v.z + w0v.w*x0v.w;
            h1 += w1v.x*x1v.x + w1v.y*x1v.y + w1v.z*x1v.z + w1v.w*x1v.w;
            h2 += w2v.x*x2v.x + w2v.y*x2v.y + w2v.z*x2v.z + w2v.w*x2v.w;
            h3 += w3v.x*x3v.x + w3v.y*x3v.y + w3v.z*x3v.z + w3v.w*x3v.w;
        }
    }
    const float itemf = tanhf((h0 + h1) + (h2 + h3));

    float d = user_emb[(size_t)user * DIM + lane] * itemf;
    d += __shfl_xor(d, 1);
    d += __shfl_xor(d, 2);
    d += __shfl_xor(d, 4);
    d += __shfl_xor(d, 8);
    d += __shfl_xor(d, 16);
    d += __shfl_xor(d, 32);
    if (lane == 0) out[p] = 1.f / (1.f + expf(-d));
}

// ============================================================================
// Fallback (verified R5 kernel) in case ws_size < table sizes.
// ============================================================================
__global__ __launch_bounds__(256, 4) void kgcn_fallback(
    const int* __restrict__ pairs, const int* __restrict__ adj_entity,
    const int* __restrict__ adj_relation, const float* __restrict__ entity_emb,
    const float* __restrict__ relation_emb, const float* __restrict__ user_emb,
    const float* __restrict__ W, const float* __restrict__ bias,
    float* __restrict__ out, int nPairs)
{
    __shared__ float ev1_s[2][KN * DIM];
    __shared__ float xb_s[4][DIM];
    const int tid = threadIdx.x, wave = tid >> 6, lane = tid & 63;
    const int q = wave >> 1, half = wave & 1;
    int p = blockIdx.x * 2 + q;
    if (p >= nPairs) p = nPairs - 1;
    float* ev1 = ev1_s[q]; float* xb = xb_s[wave];
    const int user = pairs[2 * p + 0], item = pairs[2 * p + 1];
    const float bval = bias[lane];
    const float* emb_l = entity_emb + lane;
    const float4* W4 = (const float4*)(W + lane * DIM);
    int rk0 = 0, e1 = 0;
    if (lane < KN) {
        rk0 = adj_relation[(size_t)item * KN + lane];
        e1  = adj_entity[(size_t)item * KN + lane];
    }
    float acc;
    {
        const int r = lane >> 1, hlf = lane & 1;
        const float4* rel4 = (const float4*)(relation_emb + r * DIM + hlf * 32);
        const float4* u4 = (const float4*)(user_emb + (size_t)user * DIM + hlf * 32);
        float a0 = 0.f, a1 = 0.f;
        #pragma unroll
        for (int j = 0; j < 8; j += 2) {
            float4 a = rel4[j], b = u4[j], c = rel4[j+1], d = u4[j+1];
            a0 += a.x*b.x + a.y*b.y + a.z*b.z + a.w*b.w;
            a1 += c.x*d.x + c.y*d.y + c.z*d.z + c.w*d.w;
        }
        acc = a0 + a1; acc += __shfl_xor(acc, 1);
    }
    auto softmax16 = [&](float s) -> float {
        float mx = s;
        mx = fmaxf(mx, __shfl_xor(mx, 1)); mx = fmaxf(mx, __shfl_xor(mx, 2));
        mx = fmaxf(mx, __shfl_xor(mx, 4)); mx = fmaxf(mx, __shfl_xor(mx, 8));
        float e = __expf(s - mx);
        float ss = e;
        ss += __shfl_xor(ss, 1); ss += __shfl_xor(ss, 2);
        ss += __shfl_xor(ss, 4); ss += __shfl_xor(ss, 8);
        return e * frcp(ss);
    };
    auto matvec = [&](float xv) -> float {
        asm volatile("s_waitcnt lgkmcnt(0)" ::: "memory");
        xb[lane] = xv;
        asm volatile("s_waitcnt lgkmcnt(0)" ::: "memory");
        float h0 = bval, h1 = 0.f, h2 = 0.f, h3 = 0.f;
        const float4* xv4 = (const float4*)xb;
        #pragma unroll
        for (int j = 0; j < 16; j += 4) {
            float4 w0 = W4[j], x0 = xv4[j], w1 = W4[j+1], x1 = xv4[j+1];
            float4 w2 = W4[j+2], x2 = xv4[j+2], w3 = W4[j+3], x3 = xv4[j+3];
            h0 += w0.x*x0.x + w0.y*x0.y + w0.z*x0.z + w0.w*x0.w;
            h1 += w1.x*x1.x + w1.y*x1.y + w1.z*x1.z + w1.w*x1.w;
            h2 += w2.x*x2.x + w2.y*x2.y + w2.z*x2.z + w2.w*x2.w;
            h3 += w3.x*x3.x + w3.y*x3.y + w3.z*x3.z + w3.w*x3.w;
        }
        return (h0 + h1) + (h2 + h3);
    };
    auto gather = [&](int self, int ek, float w) -> float {
        float xa = emb_l[(size_t)(unsigned)self * DIM], xc = 0.f;
        #pragma unroll
        for (int k = 0; k < KN; k += 2) {
            const int e0i = __shfl(ek, k); const float f0 = __shfl(w, k);
            const int e1i = __shfl(ek, k + 1); const float f1 = __shfl(w, k + 1);
            xa += f0 * emb_l[(size_t)(unsigned)e0i * DIM];
            xc += f1 * emb_l[(size_t)(unsigned)e1i * DIM];
        }
        return xa + xc;
    };
    int rk_n = 0, ek_n = 0;
    {
        const int g0 = __shfl(e1, half * 8);
        if (lane < KN) {
            rk_n = adj_relation[(size_t)(unsigned)g0 * KN + lane];
            ek_n = adj_entity[(size_t)(unsigned)g0 * KN + lane];
        }
    }
    #pragma unroll 1
    for (int mi = 0; mi < 8; ++mi) {
        const int m = half * 8 + mi;
        const int g = __shfl(e1, m);
        const int rk = rk_n, ek = ek_n;
        if (mi + 1 < 8) {
            const int gn = __shfl(e1, m + 1);
            if (lane < KN) {
                rk_n = adj_relation[(size_t)(unsigned)gn * KN + lane];
                ek_n = adj_entity[(size_t)(unsigned)gn * KN + lane];
            }
        }
        const float w = softmax16(__shfl(acc, rk << 1));
        const float x = gather(g, ek, w);
        ev1[m * DIM + lane] = fmaxf(matvec(x), 0.f);
    }
    __syncthreads();
    if (half != 0) return;
    const float w0 = softmax16(__shfl(acc, rk0 << 1));
    const float x0 = gather(item, e1, w0);
    const float e0 = fmaxf(matvec(x0), 0.f);
    float xa = e0, xc = 0.f;
    #pragma unroll
    for (int k = 0; k < KN; k += 2) {
        xa += __shfl(w0, k) * ev1[k * DIM + lane];
        xc += __shfl(w0, k + 1) * ev1[(k + 1) * DIM + lane];
    }
    const float itemf = tanhf(matvec(xa + xc));
    float d = user_emb[(size_t)user * DIM + lane] * itemf;
    d += __shfl_xor(d, 1); d += __shfl_xor(d, 2); d += __shfl_xor(d, 4);
    d += __shfl_xor(d, 8); d += __shfl_xor(d, 16); d += __shfl_xor(d, 32);
    if (lane == 0) out[p] = 1.f / (1.f + expf(-d));
}

extern "C" void kernel_launch(void* const* d_in, const int* in_sizes, int n_in,
                              void* d_out, int out_size, void* d_ws, size_t ws_size,
                              hipStream_t stream) {
    const int*   pairs        = (const int*)d_in[0];
    const int*   adj_entity   = (const int*)d_in[1];
    const int*   adj_relation = (const int*)d_in[2];
    const float* entity_emb   = (const float*)d_in[3];
    const float* relation_emb = (const float*)d_in[4];
    const float* user_emb     = (const float*)d_in[5];
    const float* W            = (const float*)d_in[6];
    const float* b            = (const float*)d_in[7];
    float* out = (float*)d_out;

    const int nPairs = in_sizes[0] / 2;          // pairs is (B, 2)
    const int nEnt   = in_sizes[3] / DIM;        // entity count
    const size_t recBytes = (size_t)nEnt * 128;  // merged 128B records

    if (ws_size >= recBytes) {
        unsigned char* rec = (unsigned char*)d_ws;
        const int nTiles = (nEnt + 15) >> 4;
        int preBlocks = (nTiles + 7) / 8;        // 2 tiles/wave, 4 waves/block
        const int adjBlocks = (nEnt + 255) / 256; // 1 row/thread for adj pack
        if (adjBlocks > preBlocks) preBlocks = adjBlocks;
        we_kernel_mfma<<<preBlocks, 256, 0, stream>>>(entity_emb, W,
                                                      adj_entity, adj_relation,
                                                      rec, nEnt);
        const int mainBlocks = (nPairs + 3) / 4;  // 1 wave/pair
        kgcn_main<<<mainBlocks, 256, 0, stream>>>(pairs, (const unsigned*)rec,
                                                  relation_emb, user_emb,
                                                  W, b, out, nPairs);
    } else {
        const int nBlocks = (nPairs + 1) / 2;
        kgcn_fallback<<<nBlocks, 256, 0, stream>>>(pairs, adj_entity, adj_relation,
                                                   entity_emb, relation_emb, user_emb,
                                                   W, b, out, nPairs);
    }
}

// Round 12
// 124.565 us; speedup vs baseline: 1.0564x; 1.0271x over previous
//
#include <hip/hip_runtime.h>
#include <hip/hip_bf16.h>
#include <math.h>

#define DIM  64
#define KN   16
#define NREL 32
#define S8   0.00390625f   // 2^-8: undo the x256 storage scale of WE8

__device__ __forceinline__ float frcp(float x) { return __builtin_amdgcn_rcpf(x); }

__device__ __forceinline__ unsigned short f2bf(float f) {
    unsigned u = __float_as_uint(f);
    u = (u + 0x7fffu + ((u >> 16) & 1u)) >> 16;   // RNE
    return (unsigned short)u;
}

typedef __attribute__((ext_vector_type(8))) short bfrag;   // 8 bf16 (4 VGPRs)
typedef __attribute__((ext_vector_type(4))) float f32x4;   // MFMA accumulator
typedef __attribute__((ext_vector_type(2))) float f32x2;   // fp8 cvt result

// ============================================================================
// Kernel 1 (R19 FINAL, verified 126.43us e2e): WE precompute as MFMA GEMM ->
// fp8 e4m3 table stored x256 (lifts xavier-scale values out of e4m3's
// subnormal zone into full-mantissa range) + packed adjacency
// adjP[i] = (adjE[i]<<5)|adjR[i]. Hot set = WE8 6.4MB + adjP 6.4MB = 12.8MB;
// hot-set shrinkage -> per-XCD L2 hit rate was the session's one verified
// lever (R19 -3.6us; fp4 decode-cost regressed; line-merge null).
// ============================================================================
__global__ __launch_bounds__(256, 2) void we_kernel_mfma(
    const float* __restrict__ entity_emb,
    const float* __restrict__ W,
    const int* __restrict__ adjE,
    const int* __restrict__ adjR,
    unsigned char* __restrict__ WE8,
    int* __restrict__ adjP,
    int nRows)
{
    const int tid  = threadIdx.x;
    const int wave = tid >> 6;
    const int lane = tid & 63;
    const int c = lane & 15;
    const int g = lane >> 4;

    // ---- pack adjacency: 8 entries per thread, int4 vectorized ----
    {
        const size_t nEntries = (size_t)nRows * KN;
        const size_t base = ((size_t)blockIdx.x * 256 + tid) * 8;
        if (base + 8 <= nEntries) {
            const int4* e4 = (const int4*)(adjE + base);
            const int4* r4 = (const int4*)(adjR + base);
            const int4 e0 = e4[0], e1v = e4[1];
            const int4 r0 = r4[0], r1v = r4[1];
            int4 p0, p1;
            p0.x = (e0.x << 5) | r0.x;  p0.y = (e0.y << 5) | r0.y;
            p0.z = (e0.z << 5) | r0.z;  p0.w = (e0.w << 5) | r0.w;
            p1.x = (e1v.x << 5) | r1v.x; p1.y = (e1v.y << 5) | r1v.y;
            p1.z = (e1v.z << 5) | r1v.z; p1.w = (e1v.w << 5) | r1v.w;
            ((int4*)(adjP + base))[0] = p0;
            ((int4*)(adjP + base))[1] = p1;
        } else if (base < nEntries) {
            for (size_t i = base; i < nEntries; ++i)
                adjP[i] = (adjE[i] << 5) | adjR[i];
        }
    }

    const int nTiles = (nRows + 15) >> 4;
    const int t0 = (blockIdx.x * 4 + wave) * 2;       // 2 tiles per wave
    if (t0 >= nTiles) return;

    bfrag a[4][2];
    #pragma unroll
    for (int m = 0; m < 4; ++m) {
        #pragma unroll
        for (int ks = 0; ks < 2; ++ks) {
            const float4* ws = (const float4*)(W + (size_t)(16 * m + c) * DIM + 8 * g + 32 * ks);
            const float4 w0 = ws[0], w1 = ws[1];
            a[m][ks][0] = (short)f2bf(w0.x); a[m][ks][1] = (short)f2bf(w0.y);
            a[m][ks][2] = (short)f2bf(w0.z); a[m][ks][3] = (short)f2bf(w0.w);
            a[m][ks][4] = (short)f2bf(w1.x); a[m][ks][5] = (short)f2bf(w1.y);
            a[m][ks][6] = (short)f2bf(w1.z); a[m][ks][7] = (short)f2bf(w1.w);
        }
    }

    float4 pe[2][4];
    #pragma unroll
    for (int j = 0; j < 2; ++j) {
        const int t = (t0 + j < nTiles) ? (t0 + j) : 0;
        int row = 16 * t + c;
        if (row >= nRows) row = nRows - 1;
        const float4* src = (const float4*)(entity_emb + (size_t)row * DIM + 8 * g);
        pe[j][0] = src[0];
        pe[j][1] = src[1];
        pe[j][2] = src[8];
        pe[j][3] = src[9];
    }

    #pragma unroll
    for (int j = 0; j < 2; ++j) {
        const int t = t0 + j;
        if (t >= nTiles) continue;

        bfrag b0, b1;
        b0[0] = (short)f2bf(pe[j][0].x); b0[1] = (short)f2bf(pe[j][0].y);
        b0[2] = (short)f2bf(pe[j][0].z); b0[3] = (short)f2bf(pe[j][0].w);
        b0[4] = (short)f2bf(pe[j][1].x); b0[5] = (short)f2bf(pe[j][1].y);
        b0[6] = (short)f2bf(pe[j][1].z); b0[7] = (short)f2bf(pe[j][1].w);
        b1[0] = (short)f2bf(pe[j][2].x); b1[1] = (short)f2bf(pe[j][2].y);
        b1[2] = (short)f2bf(pe[j][2].z); b1[3] = (short)f2bf(pe[j][2].w);
        b1[4] = (short)f2bf(pe[j][3].x); b1[5] = (short)f2bf(pe[j][3].y);
        b1[6] = (short)f2bf(pe[j][3].z); b1[7] = (short)f2bf(pe[j][3].w);

        f32x4 acc[4];
        #pragma unroll
        for (int m = 0; m < 4; ++m) {
            f32x4 z = {0.f, 0.f, 0.f, 0.f};
            z = __builtin_amdgcn_mfma_f32_16x16x32_bf16(a[m][0], b0, z, 0, 0, 0);
            z = __builtin_amdgcn_mfma_f32_16x16x32_bf16(a[m][1], b1, z, 0, 0, 0);
            acc[m] = z;
        }

        const int erow = 16 * t + c;
        if (erow < nRows) {
            #pragma unroll
            for (int m = 0; m < 4; ++m) {
                // fp8 e4m3 row, values x256 (into normal range), 4 dims/dword
                int r8 = 0;
                r8 = __builtin_amdgcn_cvt_pk_fp8_f32(acc[m][0] * 256.f, acc[m][1] * 256.f, r8, false);
                r8 = __builtin_amdgcn_cvt_pk_fp8_f32(acc[m][2] * 256.f, acc[m][3] * 256.f, r8, true);
                *(unsigned*)(WE8 + (size_t)erow * DIM + 16 * m + 4 * g) = (unsigned)r8;
            }
        }
    }
}

// ============================================================================
// Kernel 2 (R19 FINAL): all WE reads from the 6.4MB scaled-fp8 table (64B
// rows, 4B/lane gathers, free hw decode via v_cvt_pk_f32_fp8). Structure =
// verified R14/R16 batched issue-then-consume, 1 wave/pair, no barriers.
// ============================================================================
__global__ __launch_bounds__(256, 4) void kgcn_main(
    const int* __restrict__ pairs,
    const int* __restrict__ adjP,
    const unsigned char* __restrict__ WE8,
    const float* __restrict__ relation_emb,
    const float* __restrict__ user_emb,
    const float* __restrict__ W,
    const float* __restrict__ bias,
    float* __restrict__ out,
    int nPairs)
{
    __shared__ float ev1_s[4][KN * DIM];  // per-wave layer-0 outputs
    __shared__ float xb_s[4][DIM];        // per-wave matvec broadcast buffer

    const int tid  = threadIdx.x;
    const int wave = tid >> 6;
    const int lane = tid & 63;
    const int p    = blockIdx.x * 4 + wave;
    if (p >= nPairs) return;              // no barriers -> safe early-out

    float* ev1 = ev1_s[wave];
    float* xb  = xb_s[wave];

    const int qq = lane >> 4;             // quarter-wave id (0..3)
    const int c  = lane & 15;             // dword column within a WE8 row
    const int c4 = c * 4;                 // first owned dim

    const int user = pairs[2 * p + 0];
    const int item = pairs[2 * p + 1];

    const float4 b4 = *(const float4*)(bias + c4);
    const unsigned* W8q = (const unsigned*)WE8;   // fp8 row = 16 dwords (64B)

    // ---- chase root: item packed adjacency row (single load) ----
    int rk0 = 0, e1 = 0;
    if (lane < KN) {
        const int pk0 = adjP[(size_t)item * KN + lane];
        rk0 = pk0 & 31;
        e1  = pk0 >> 5;
    }

    // ---- independent: user/relation rows into regs (fly during e1 wait) ----
    float4 rr[8], ur[8];
    {
        const int r = lane >> 1, hlf = lane & 1;
        const float4* rel4 = (const float4*)(relation_emb + r * DIM + hlf * 32);
        const float4* u4   = (const float4*)(user_emb + (size_t)user * DIM + hlf * 32);
        #pragma unroll
        for (int j = 0; j < 8; ++j) { rr[j] = rel4[j]; ur[j] = u4[j]; }
    }

    // ---- e1 arrival gates: hop-0 rows + slot adjacency (issue ASAP) ----
    const unsigned itemv8 = W8q[(size_t)item * 16 + c];
    unsigned h0v8[4];
    #pragma unroll
    for (int k = 0; k < 4; ++k) {
        const int e = __shfl(e1, qq * 4 + k);
        h0v8[k] = W8q[(size_t)(unsigned)e * 16 + c];
    }
    int rkA[4], ekA[4], gsA[4];
    #pragma unroll
    for (int s = 0; s < 4; ++s) {
        gsA[s] = __shfl(e1, 4 * s + qq);
        const int pk = adjP[(size_t)(unsigned)gsA[s] * KN + c];
        rkA[s] = pk & 31;
        ekA[s] = pk >> 5;
    }

    // ---- dot(u, rel_r) ----
    float acc;
    {
        float a0 = 0.f, a1 = 0.f;
        #pragma unroll
        for (int j = 0; j < 8; j += 2) {
            float4 a = rr[j],     b = ur[j];
            float4 cc = rr[j+1],  d = ur[j+1];
            a0 += a.x*b.x + a.y*b.y + a.z*b.z + a.w*b.w;
            a1 += cc.x*d.x + cc.y*d.y + cc.z*d.z + cc.w*d.w;
        }
        acc = a0 + a1;
        acc += __shfl_xor(acc, 1);
    }

    // ---- ISSUE hop-1 gathers for slots 0..2 + self rows (4 B/lane) ----
    unsigned svA8[4];
    unsigned nvA[3][KN];
    #pragma unroll
    for (int s = 0; s < 3; ++s) {
        svA8[s] = W8q[(size_t)(unsigned)gsA[s] * 16 + c];
        #pragma unroll
        for (int k = 0; k < KN; ++k) {
            const int e = __shfl(ekA[s], qq * 16 + k);
            nvA[s][k] = W8q[(size_t)(unsigned)e * 16 + c];
        }
    }
    svA8[3] = W8q[(size_t)(unsigned)gsA[3] * 16 + c];

    // softmax within 16-lane subgroups (4 independent groups per call)
    auto softmax16 = [&](float s) -> float {
        float mx = s;
        mx = fmaxf(mx, __shfl_xor(mx, 1));
        mx = fmaxf(mx, __shfl_xor(mx, 2));
        mx = fmaxf(mx, __shfl_xor(mx, 4));
        mx = fmaxf(mx, __shfl_xor(mx, 8));
        float e = __expf(s - mx);
        float ss = e;
        ss += __shfl_xor(ss, 1);
        ss += __shfl_xor(ss, 2);
        ss += __shfl_xor(ss, 4);
        ss += __shfl_xor(ss, 8);
        return e * frcp(ss);
    };

    // ---- softmaxes run UNDER the gather flight ----
    float wA[4];
    #pragma unroll
    for (int s = 0; s < 4; ++s) wA[s] = softmax16(__shfl(acc, rkA[s] << 1)) * S8;
    const float w0 = softmax16(__shfl(acc, rk0 << 1));   // unscaled: also weights f32 ev1

    // ---- consume slot 0, then issue slot 3's neighbors ----
    {
        const f32x2 slo = __builtin_amdgcn_cvt_pk_f32_fp8(svA8[0], false);
        const f32x2 shi = __builtin_amdgcn_cvt_pk_f32_fp8(svA8[0], true);
        float ax = b4.x + S8 * slo.x;
        float ay = b4.y + S8 * slo.y;
        float az = b4.z + S8 * shi.x;
        float aw = b4.w + S8 * shi.y;
        #pragma unroll
        for (int k = 0; k < KN; ++k) {
            const float w = __shfl(wA[0], qq * 16 + k);
            const f32x2 lo = __builtin_amdgcn_cvt_pk_f32_fp8(nvA[0][k], false);
            const f32x2 hi = __builtin_amdgcn_cvt_pk_f32_fp8(nvA[0][k], true);
            ax += w * lo.x;
            ay += w * lo.y;
            az += w * hi.x;
            aw += w * hi.y;
        }
        *(float4*)&ev1[qq * DIM + c4] =
            make_float4(fmaxf(ax, 0.f), fmaxf(ay, 0.f), fmaxf(az, 0.f), fmaxf(aw, 0.f));
    }
    unsigned nv3[KN];
    #pragma unroll
    for (int k = 0; k < KN; ++k) {
        const int e = __shfl(ekA[3], qq * 16 + k);
        nv3[k] = W8q[(size_t)(unsigned)e * 16 + c];
    }
    #pragma unroll
    for (int s = 1; s < 3; ++s) {
        const f32x2 slo = __builtin_amdgcn_cvt_pk_f32_fp8(svA8[s], false);
        const f32x2 shi = __builtin_amdgcn_cvt_pk_f32_fp8(svA8[s], true);
        float ax = b4.x + S8 * slo.x;
        float ay = b4.y + S8 * slo.y;
        float az = b4.z + S8 * shi.x;
        float aw = b4.w + S8 * shi.y;
        #pragma unroll
        for (int k = 0; k < KN; ++k) {
            const float w = __shfl(wA[s], qq * 16 + k);
            const f32x2 lo = __builtin_amdgcn_cvt_pk_f32_fp8(nvA[s][k], false);
            const f32x2 hi = __builtin_amdgcn_cvt_pk_f32_fp8(nvA[s][k], true);
            ax += w * lo.x;
            ay += w * lo.y;
            az += w * hi.x;
            aw += w * hi.y;
        }
        *(float4*)&ev1[(4 * s + qq) * DIM + c4] =
            make_float4(fmaxf(ax, 0.f), fmaxf(ay, 0.f), fmaxf(az, 0.f), fmaxf(aw, 0.f));
    }
    {
        const f32x2 slo = __builtin_amdgcn_cvt_pk_f32_fp8(svA8[3], false);
        const f32x2 shi = __builtin_amdgcn_cvt_pk_f32_fp8(svA8[3], true);
        float ax = b4.x + S8 * slo.x;
        float ay = b4.y + S8 * slo.y;
        float az = b4.z + S8 * shi.x;
        float aw = b4.w + S8 * shi.y;
        #pragma unroll
        for (int k = 0; k < KN; ++k) {
            const float w = __shfl(wA[3], qq * 16 + k);
            const f32x2 lo = __builtin_amdgcn_cvt_pk_f32_fp8(nv3[k], false);
            const f32x2 hi = __builtin_amdgcn_cvt_pk_f32_fp8(nv3[k], true);
            ax += w * lo.x;
            ay += w * lo.y;
            az += w * hi.x;
            aw += w * hi.y;
        }
        *(float4*)&ev1[(12 + qq) * DIM + c4] =
            make_float4(fmaxf(ax, 0.f), fmaxf(ay, 0.f), fmaxf(az, 0.f), fmaxf(aw, 0.f));
    }

    // ---- hop 0, layer 0: accumulate the preloaded fp8 rows ----
    float ax = 0.f, ay = 0.f, az = 0.f, aw = 0.f;
    #pragma unroll
    for (int k = 0; k < 4; ++k) {
        const float w = __shfl(w0, qq * 4 + k) * S8;
        const f32x2 lo = __builtin_amdgcn_cvt_pk_f32_fp8(h0v8[k], false);
        const f32x2 hi = __builtin_amdgcn_cvt_pk_f32_fp8(h0v8[k], true);
        ax += w * lo.x;
        ay += w * lo.y;
        az += w * hi.x;
        aw += w * hi.y;
    }
    ax += __shfl_xor(ax, 16); ay += __shfl_xor(ay, 16);
    az += __shfl_xor(az, 16); aw += __shfl_xor(aw, 16);
    ax += __shfl_xor(ax, 32); ay += __shfl_xor(ay, 32);
    az += __shfl_xor(az, 32); aw += __shfl_xor(aw, 32);
    {
        const f32x2 ilo = __builtin_amdgcn_cvt_pk_f32_fp8(itemv8, false);
        const f32x2 ihi = __builtin_amdgcn_cvt_pk_f32_fp8(itemv8, true);
        ax += S8 * ilo.x + b4.x;
        ay += S8 * ilo.y + b4.y;
        az += S8 * ihi.x + b4.z;
        aw += S8 * ihi.y + b4.w;
    }
    const float e0x = fmaxf(ax, 0.f), e0y = fmaxf(ay, 0.f);
    const float e0z = fmaxf(az, 0.f), e0w = fmaxf(aw, 0.f);

    // ---- layer 1 aggregate: x1 = e0 + sum_k w0_k * ev1_k (f32, unscaled w0)
    asm volatile("s_waitcnt lgkmcnt(0)" ::: "memory");  // ev1 writes done (wave-local)
    float sx = 0.f, sy = 0.f, sz = 0.f, sw = 0.f;
    #pragma unroll
    for (int k = 0; k < 4; ++k) {
        const int   kg = qq * 4 + k;
        const float w  = __shfl(w0, kg);
        float4 ev = *(const float4*)&ev1[kg * DIM + c4];
        sx += w * ev.x;
        sy += w * ev.y;
        sz += w * ev.z;
        sw += w * ev.w;
    }
    sx += __shfl_xor(sx, 16); sy += __shfl_xor(sy, 16);
    sz += __shfl_xor(sz, 16); sw += __shfl_xor(sw, 16);
    sx += __shfl_xor(sx, 32); sy += __shfl_xor(sy, 32);
    sz += __shfl_xor(sz, 32); sw += __shfl_xor(sw, 32);

    // ---- the ONE real matvec: h1 = W x1 + b, via LDS broadcast ----
    asm volatile("s_waitcnt lgkmcnt(0)" ::: "memory");
    if (qq == 0)
        *(float4*)&xb[c4] = make_float4(e0x + sx, e0y + sy, e0z + sz, e0w + sw);
    asm volatile("s_waitcnt lgkmcnt(0)" ::: "memory");
    float h0 = bias[lane], h1 = 0.f, h2 = 0.f, h3 = 0.f;
    {
        const float4* Wl  = (const float4*)(W + lane * DIM);
        const float4* xv4 = (const float4*)xb;
        #pragma unroll
        for (int j = 0; j < 16; j += 4) {
            float4 w0v = Wl[j],   x0v = xv4[j];
            float4 w1v = Wl[j+1], x1v = xv4[j+1];
            float4 w2v = Wl[j+2], x2v = xv4[j+2];
            float4 w3v = Wl[j+3], x3v = xv4[j+3];
            h0 += w0v.x*x0v.x + w0v.y*x0v.y + w0v.z*x0v.z + w0v.w*x0v.w;
            h1 += w1v.x*x1v.x + w1v.y*x1v.y + w1v.z*x1v.z + w1v.w*x1v.w;
            h2 += w2v.x*x2v.x + w2v.y*x2v.y + w2v.z*x2v.z + w2v.w*x2v.w;
            h3 += w3v.x*x3v.x + w3v.y*x3v.y + w3v.z*x3v.z + w3v.w*x3v.w;
        }
    }
    const float itemf = tanhf((h0 + h1) + (h2 + h3));

    float d = user_emb[(size_t)user * DIM + lane] * itemf;
    d += __shfl_xor(d, 1);
    d += __shfl_xor(d, 2);
    d += __shfl_xor(d, 4);
    d += __shfl_xor(d, 8);
    d += __shfl_xor(d, 16);
    d += __shfl_xor(d, 32);
    if (lane == 0) out[p] = 1.f / (1.f + expf(-d));
}

// ============================================================================
// Fallback (verified R5 kernel) in case ws_size < table sizes.
// ============================================================================
__global__ __launch_bounds__(256, 4) void kgcn_fallback(
    const int* __restrict__ pairs, const int* __restrict__ adj_entity,
    const int* __restrict__ adj_relation, const float* __restrict__ entity_emb,
    const float* __restrict__ relation_emb, const float* __restrict__ user_emb,
    const float* __restrict__ W, const float* __restrict__ bias,
    float* __restrict__ out, int nPairs)
{
    __shared__ float ev1_s[2][KN * DIM];
    __shared__ float xb_s[4][DIM];
    const int tid = threadIdx.x, wave = tid >> 6, lane = tid & 63;
    const int q = wave >> 1, half = wave & 1;
    int p = blockIdx.x * 2 + q;
    if (p >= nPairs) p = nPairs - 1;
    float* ev1 = ev1_s[q]; float* xb = xb_s[wave];
    const int user = pairs[2 * p + 0], item = pairs[2 * p + 1];
    const float bval = bias[lane];
    const float* emb_l = entity_emb + lane;
    const float4* W4 = (const float4*)(W + lane * DIM);
    int rk0 = 0, e1 = 0;
    if (lane < KN) {
        rk0 = adj_relation[(size_t)item * KN + lane];
        e1  = adj_entity[(size_t)item * KN + lane];
    }
    float acc;
    {
        const int r = lane >> 1, hlf = lane & 1;
        const float4* rel4 = (const float4*)(relation_emb + r * DIM + hlf * 32);
        const float4* u4 = (const float4*)(user_emb + (size_t)user * DIM + hlf * 32);
        float a0 = 0.f, a1 = 0.f;
        #pragma unroll
        for (int j = 0; j < 8; j += 2) {
            float4 a = rel4[j], b = u4[j], c = rel4[j+1], d = u4[j+1];
            a0 += a.x*b.x + a.y*b.y + a.z*b.z + a.w*b.w;
            a1 += c.x*d.x + c.y*d.y + c.z*d.z + c.w*d.w;
        }
        acc = a0 + a1; acc += __shfl_xor(acc, 1);
    }
    auto softmax16 = [&](float s) -> float {
        float mx = s;
        mx = fmaxf(mx, __shfl_xor(mx, 1)); mx = fmaxf(mx, __shfl_xor(mx, 2));
        mx = fmaxf(mx, __shfl_xor(mx, 4)); mx = fmaxf(mx, __shfl_xor(mx, 8));
        float e = __expf(s - mx);
        float ss = e;
        ss += __shfl_xor(ss, 1); ss += __shfl_xor(ss, 2);
        ss += __shfl_xor(ss, 4); ss += __shfl_xor(ss, 8);
        return e * frcp(ss);
    };
    auto matvec = [&](float xv) -> float {
        asm volatile("s_waitcnt lgkmcnt(0)" ::: "memory");
        xb[lane] = xv;
        asm volatile("s_waitcnt lgkmcnt(0)" ::: "memory");
        float h0 = bval, h1 = 0.f, h2 = 0.f, h3 = 0.f;
        const float4* xv4 = (const float4*)xb;
        #pragma unroll
        for (int j = 0; j < 16; j += 4) {
            float4 w0 = W4[j], x0 = xv4[j], w1 = W4[j+1], x1 = xv4[j+1];
            float4 w2 = W4[j+2], x2 = xv4[j+2], w3 = W4[j+3], x3 = xv4[j+3];
            h0 += w0.x*x0.x + w0.y*x0.y + w0.z*x0.z + w0.w*x0.w;
            h1 += w1.x*x1.x + w1.y*x1.y + w1.z*x1.z + w1.w*x1.w;
            h2 += w2.x*x2.x + w2.y*x2.y + w2.z*x2.z + w2.w*x2.w;
            h3 += w3.x*x3.x + w3.y*x3.y + w3.z*x3.z + w3.w*x3.w;
        }
        return (h0 + h1) + (h2 + h3);
    };
    auto gather = [&](int self, int ek, float w) -> float {
        float xa = emb_l[(size_t)(unsigned)self * DIM], xc = 0.f;
        #pragma unroll
        for (int k = 0; k < KN; k += 2) {
            const int e0i = __shfl(ek, k); const float f0 = __shfl(w, k);
            const int e1i = __shfl(ek, k + 1); const float f1 = __shfl(w, k + 1);
            xa += f0 * emb_l[(size_t)(unsigned)e0i * DIM];
            xc += f1 * emb_l[(size_t)(unsigned)e1i * DIM];
        }
        return xa + xc;
    };
    int rk_n = 0, ek_n = 0;
    {
        const int g0 = __shfl(e1, half * 8);
        if (lane < KN) {
            rk_n = adj_relation[(size_t)(unsigned)g0 * KN + lane];
            ek_n = adj_entity[(size_t)(unsigned)g0 * KN + lane];
        }
    }
    #pragma unroll 1
    for (int mi = 0; mi < 8; ++mi) {
        const int m = half * 8 + mi;
        const int g = __shfl(e1, m);
        const int rk = rk_n, ek = ek_n;
        if (mi + 1 < 8) {
            const int gn = __shfl(e1, m + 1);
            if (lane < KN) {
                rk_n = adj_relation[(size_t)(unsigned)gn * KN + lane];
                ek_n = adj_entity[(size_t)(unsigned)gn * KN + lane];
            }
        }
        const float w = softmax16(__shfl(acc, rk << 1));
        const float x = gather(g, ek, w);
        ev1[m * DIM + lane] = fmaxf(matvec(x), 0.f);
    }
    __syncthreads();
    if (half != 0) return;
    const float w0 = softmax16(__shfl(acc, rk0 << 1));
    const float x0 = gather(item, e1, w0);
    const float e0 = fmaxf(matvec(x0), 0.f);
    float xa = e0, xc = 0.f;
    #pragma unroll
    for (int k = 0; k < KN; k += 2) {
        xa += __shfl(w0, k) * ev1[k * DIM + lane];
        xc += __shfl(w0, k + 1) * ev1[(k + 1) * DIM + lane];
    }
    const float itemf = tanhf(matvec(xa + xc));
    float d = user_emb[(size_t)user * DIM + lane] * itemf;
    d += __shfl_xor(d, 1); d += __shfl_xor(d, 2); d += __shfl_xor(d, 4);
    d += __shfl_xor(d, 8); d += __shfl_xor(d, 16); d += __shfl_xor(d, 32);
    if (lane == 0) out[p] = 1.f / (1.f + expf(-d));
}

extern "C" void kernel_launch(void* const* d_in, const int* in_sizes, int n_in,
                              void* d_out, int out_size, void* d_ws, size_t ws_size,
                              hipStream_t stream) {
    const int*   pairs        = (const int*)d_in[0];
    const int*   adj_entity   = (const int*)d_in[1];
    const int*   adj_relation = (const int*)d_in[2];
    const float* entity_emb   = (const float*)d_in[3];
    const float* relation_emb = (const float*)d_in[4];
    const float* user_emb     = (const float*)d_in[5];
    const float* W            = (const float*)d_in[6];
    const float* b            = (const float*)d_in[7];
    float* out = (float*)d_out;

    const int nPairs = in_sizes[0] / 2;          // pairs is (B, 2)
    const int nEnt   = in_sizes[3] / DIM;        // entity count
    const size_t w8Bytes   = (size_t)in_sizes[3] * sizeof(unsigned char);
    const size_t w8Aligned = (w8Bytes + 255) & ~(size_t)255;
    const size_t adjBytes  = (size_t)nEnt * KN * sizeof(int);

    if (ws_size >= w8Aligned + adjBytes) {
        unsigned char* WE8 = (unsigned char*)d_ws;
        int* adjP = (int*)((char*)d_ws + w8Aligned);
        const int nTiles = (nEnt + 15) >> 4;
        const int preBlocks = (nTiles + 7) / 8;   // 2 tiles/wave, 4 waves/block
        we_kernel_mfma<<<preBlocks, 256, 0, stream>>>(entity_emb, W,
                                                      adj_entity, adj_relation,
                                                      WE8, adjP, nEnt);
        const int mainBlocks = (nPairs + 3) / 4;  // 1 wave/pair
        kgcn_main<<<mainBlocks, 256, 0, stream>>>(pairs, adjP,
                                                  WE8, relation_emb, user_emb,
                                                  W, b, out, nPairs);
    } else {
        const int nBlocks = (nPairs + 1) / 2;
        kgcn_fallback<<<nBlocks, 256, 0, stream>>>(pairs, adj_entity, adj_relation,
                                                   entity_emb, relation_emb, user_emb,
                                                   W, b, out, nPairs);
    }
}